// Round 9
// baseline (137.032 us; speedup 1.0000x reference)
//
#include <hip/hip_runtime.h>
#include <hip/hip_bf16.h>

// B=2, S=2048, D=1024, H=16, DH=64. out = softmax(mask(QK^T/8)) V @ Wo^T, Q=x@Wq^T etc.
// fp32 inputs (detected). Internal: bf16 MFMA, fp32 accum.
// FAST path (ws >= 48MB): fp32->bf16 convert pass, then m97-style GEMMs
//   (128x128 tile, 256 thr, global_load_lds w=16, 3 blocks/CU).
// FALLBACK path: round-8 kernels (reg-staged fp32 GEMM 128x256).
// ws: Qp [B,S,D] (pre-scaled 0.125*log2e) + Kh [B,H,S,DH] (+ fast: Qb,Kb,Vb,W*b bf16).
// d_out: Vt [B,H,DH,S] scratch, overwritten by final GEMM. AO aliases Qp.

typedef unsigned short u16;
typedef __attribute__((ext_vector_type(8))) short bf16x8;  // 8 bf16 = 4 VGPR
typedef __attribute__((ext_vector_type(4))) float f32x4;   // MFMA C/D frag
typedef __attribute__((ext_vector_type(4))) short s16x4;

#define DEVI static __device__ __forceinline__
#define SCL 0.18033688011112042f  /* 0.125 * log2(e) */
#define GLDS(g, l) __builtin_amdgcn_global_load_lds( \
    (const __attribute__((address_space(1))) unsigned*)(g), \
    (__attribute__((address_space(3))) unsigned*)(l), 16, 0, 0)

DEVI u16 f2bf(float f) {
  __hip_bfloat16 h = __float2bfloat16(f);
  union { __hip_bfloat16 h; u16 u; } c; c.h = h;
  return c.u;
}

template <int F32>
DEVI bf16x8 lda8(const void* base, size_t off) {
  if constexpr (!F32) {
    return *(const bf16x8*)((const u16*)base + off);
  } else {
    const float* p = (const float*)base + off;
    f32x4 a = *(const f32x4*)p;
    f32x4 b = *(const f32x4*)(p + 4);
    bf16x8 r;
    r[0] = (short)f2bf(a[0]); r[1] = (short)f2bf(a[1]);
    r[2] = (short)f2bf(a[2]); r[3] = (short)f2bf(a[3]);
    r[4] = (short)f2bf(b[0]); r[5] = (short)f2bf(b[1]);
    r[6] = (short)f2bf(b[2]); r[7] = (short)f2bf(b[3]);
    return r;
  }
}

// ---------------- shared epilogue (C = A @ W^T tile writer) ----------------
// MODE 0: token-major (bf16 or f32 per O32), scaled. MODE 1: Vt[((b*16+h)*64+d)*2048+s].
// MODE 2: head-major Kh[((b*16+h)*2048+s)*64+dh].
template <int MODE, int O32>
DEVI void epilogue(f32x4 (&acc)[4][4], void* C, int tileM, int tileN,
                   int wr, int wc, int lr, int lg, float oscale) {
  constexpr int N = 1024;
  if constexpr (MODE == 0) {
#pragma unroll
    for (int m = 0; m < 4; ++m) {
      const int row0 = tileM + wr + m * 16 + lg * 4;
#pragma unroll
      for (int n = 0; n < 4; ++n) {
        const int col = tileN + wc + n * 16 + lr;
#pragma unroll
        for (int j = 0; j < 4; ++j) {
          if constexpr (O32)
            ((float*)C)[(size_t)(row0 + j) * N + col] = acc[m][n][j] * oscale;
          else
            ((u16*)C)[(size_t)(row0 + j) * N + col] = f2bf(acc[m][n][j] * oscale);
        }
      }
    }
  } else if constexpr (MODE == 1) {
    u16* Cv = (u16*)C;
#pragma unroll
    for (int m = 0; m < 4; ++m) {
      const int row0 = tileM + wr + m * 16 + lg * 4;
      const int bb = row0 >> 11, s0 = row0 & 2047;
#pragma unroll
      for (int n = 0; n < 4; ++n) {
        const int col = tileN + wc + n * 16 + lr;
        s16x4 pk;
#pragma unroll
        for (int j = 0; j < 4; ++j) pk[j] = (short)f2bf(acc[m][n][j]);
        *(s16x4*)(Cv + ((size_t)(col + (bb << 10)) << 11) + s0) = pk;
      }
    }
  } else {
    u16* Cv = (u16*)C;
#pragma unroll
    for (int m = 0; m < 4; ++m) {
      const int row0 = tileM + wr + m * 16 + lg * 4;
      const int bb = row0 >> 11, s0 = row0 & 2047;
#pragma unroll
      for (int n = 0; n < 4; ++n) {
        const int col = tileN + wc + n * 16 + lr;
        const size_t base = ((size_t)((bb << 4) + (col >> 6)) * 2048 + s0) * 64 + (col & 63);
#pragma unroll
        for (int j = 0; j < 4; ++j)
          Cv[base + (size_t)j * 64] = f2bf(acc[m][n][j]);
      }
    }
  }
}

// ================= FAST PATH: bf16 GEMM, m97 structure =================
// 128x128 tile, 256 thr (4 waves, 64x64/wave), BK=32, global_load_lds w=16.
template <int MODE>
DEVI void gemm_bf16_core(u16* sA, u16* sB, const u16* __restrict__ A,
                         const u16* __restrict__ W, void* C, float oscale) {
  constexpr int K = 1024;
  const int tid = threadIdx.x;
  const int lane = tid & 63;
  const int wave = tid >> 6;
  const int lr = lane & 15, lg = lane >> 4;
  const int wr = (wave >> 1) * 64, wc = (wave & 1) * 64;
  const int tileN = blockIdx.x * 128, tileM = blockIdx.y * 128;

  // staging: 8 wave-instr units of 1KB; this wave stages units wave*2, wave*2+1
  const int u0 = wave * 2;
  const int srow0 = u0 * 16 + (lane >> 2);   // unit u covers rows u*16..u*16+15
  const int scol = (lane & 3) * 8;
  const u16* gA0 = A + (size_t)(tileM + srow0) * K + scol;
  const u16* gA1 = gA0 + (size_t)16 * K;
  const u16* gB0 = W + (size_t)(tileN + srow0) * K + scol;
  const u16* gB1 = gB0 + (size_t)16 * K;
  u16* dA0 = sA + u0 * 512;  // wave-uniform; HW adds lane*16B
  u16* dA1 = sA + u0 * 512 + 512;
  u16* dB0 = sB + u0 * 512;
  u16* dB1 = sB + u0 * 512 + 512;

  f32x4 acc[4][4] = {};

  for (int k0 = 0; k0 < K; k0 += 32) {
    __syncthreads();                 // previous iteration's readers done
    GLDS(gA0 + k0, dA0);
    GLDS(gA1 + k0, dA1);
    GLDS(gB0 + k0, dB0);
    GLDS(gB1 + k0, dB1);
    asm volatile("s_waitcnt vmcnt(0)" ::: "memory");
    __syncthreads();
    bf16x8 af[4], bfr[4];
#pragma unroll
    for (int m = 0; m < 4; ++m)
      af[m] = *(const bf16x8*)(sA + (wr + m * 16 + lr) * 32 + lg * 8);
#pragma unroll
    for (int n = 0; n < 4; ++n)
      bfr[n] = *(const bf16x8*)(sB + (wc + n * 16 + lr) * 32 + lg * 8);
#pragma unroll
    for (int m = 0; m < 4; ++m)
#pragma unroll
      for (int n = 0; n < 4; ++n)
        acc[m][n] = __builtin_amdgcn_mfma_f32_16x16x32_bf16(af[m], bfr[n], acc[m][n], 0, 0, 0);
  }
  epilogue<MODE, 0>(acc, C, tileM, tileN, wr, wc, lr, lg, oscale);
}

__global__ void __launch_bounds__(256, 3)
gemm_qkv_bf16(const u16* __restrict__ Qb, const u16* __restrict__ Wq, u16* __restrict__ Qp,
              const u16* __restrict__ Kb, const u16* __restrict__ Wk, u16* __restrict__ Kh,
              const u16* __restrict__ Vb, const u16* __restrict__ Wv, u16* __restrict__ Vt) {
  __shared__ __align__(16) u16 sA[128 * 32];
  __shared__ __align__(16) u16 sB[128 * 32];
  if (blockIdx.z == 0)      gemm_bf16_core<0>(sA, sB, Qb, Wq, Qp, SCL);
  else if (blockIdx.z == 1) gemm_bf16_core<2>(sA, sB, Kb, Wk, Kh, 1.f);
  else                      gemm_bf16_core<1>(sA, sB, Vb, Wv, Vt, 1.f);
}

__global__ void __launch_bounds__(256, 3)
gemm_out_bf16(const u16* __restrict__ A, const u16* __restrict__ W, u16* __restrict__ C) {
  __shared__ __align__(16) u16 sA[128 * 32];
  __shared__ __align__(16) u16 sB[128 * 32];
  gemm_bf16_core<0>(sA, sB, A, W, C, 1.f);
}

// fp32 -> bf16 convert: y selects tensor (0-2: 4.19M elems, 3-6: 1.05M).
__global__ void __launch_bounds__(256)
cvt_all(const float* s0, const float* s1, const float* s2, const float* s3,
        const float* s4, const float* s5, const float* s6,
        u16* d0, u16* d1, u16* d2, u16* d3, u16* d4, u16* d5, u16* d6) {
  const int y = blockIdx.y;
  const float* s; u16* d; int n;
  if (y == 0)      { s = s0; d = d0; n = 4194304; }
  else if (y == 1) { s = s1; d = d1; n = 4194304; }
  else if (y == 2) { s = s2; d = d2; n = 4194304; }
  else if (y == 3) { s = s3; d = d3; n = 1048576; }
  else if (y == 4) { s = s4; d = d4; n = 1048576; }
  else if (y == 5) { s = s5; d = d5; n = 1048576; }
  else             { s = s6; d = d6; n = 1048576; }
  const int nu = n >> 3;
  const int stride = gridDim.x * 256;
  for (int u = blockIdx.x * 256 + threadIdx.x; u < nu; u += stride) {
    const float* p = s + (size_t)u * 8;
    f32x4 a = *(const f32x4*)p;
    f32x4 b = *(const f32x4*)(p + 4);
    bf16x8 r;
    r[0] = (short)f2bf(a[0]); r[1] = (short)f2bf(a[1]);
    r[2] = (short)f2bf(a[2]); r[3] = (short)f2bf(a[3]);
    r[4] = (short)f2bf(b[0]); r[5] = (short)f2bf(b[1]);
    r[6] = (short)f2bf(b[2]); r[7] = (short)f2bf(b[3]);
    *(bf16x8*)(d + (size_t)u * 8) = r;
  }
}

// ================= FALLBACK PATH: round-8 reg-staged fp32 GEMM =================
template <int A32, int W32, int MODE, int O32>
DEVI void gemm_core(u16* sA, u16* sB, const void* A, const void* W, void* C,
                    int tileM, int tileN, float oscale) {
  constexpr int K = 1024;
  const int tid = threadIdx.x;
  const int lane = tid & 63;
  const int wave = tid >> 6;
  const int wr = (wave >> 2) * 64;
  const int wc = (wave & 3) * 64;
  const int lr = lane & 15;
  const int lg = lane >> 4;

  f32x4 acc[4][4] = {};

  const int ea = tid * 8;
  const int ra = ea >> 5, ca = ea & 31;
  const int eb1 = 4096 + tid * 8;
  const int rb1 = eb1 >> 5, cb1 = eb1 & 31;

  for (int k0 = 0; k0 < K; k0 += 32) {
    bf16x8 va  = lda8<A32>(A, (size_t)(tileM + ra) * K + ca + k0);
    bf16x8 vb0 = lda8<W32>(W, (size_t)(tileN + ra) * K + ca + k0);
    bf16x8 vb1 = lda8<W32>(W, (size_t)(tileN + rb1) * K + cb1 + k0);
    __syncthreads();
    *(bf16x8*)(sA + ea) = va;
    *(bf16x8*)(sB + ea) = vb0;
    *(bf16x8*)(sB + eb1) = vb1;
    __syncthreads();
    bf16x8 af[4], bfr[4];
#pragma unroll
    for (int m = 0; m < 4; ++m)
      af[m] = *(const bf16x8*)(sA + (wr + m * 16 + lr) * 32 + lg * 8);
#pragma unroll
    for (int n = 0; n < 4; ++n)
      bfr[n] = *(const bf16x8*)(sB + (wc + n * 16 + lr) * 32 + lg * 8);
#pragma unroll
    for (int m = 0; m < 4; ++m)
#pragma unroll
      for (int n = 0; n < 4; ++n)
        acc[m][n] = __builtin_amdgcn_mfma_f32_16x16x32_bf16(af[m], bfr[n], acc[m][n], 0, 0, 0);
  }
  epilogue<MODE, O32>(acc, C, tileM, tileN, wr, wc, lr, lg, oscale);
}

DEVI void tile_remap(int& tileM, int& tileN) {
  const int i = blockIdx.x + 4 * blockIdx.y;
  const int c = i & 7, s = i >> 3;
  tileM = (c * 4 + (s & 3)) * 128;
  tileN = (s >> 2) * 256;
}

template <int IN32>
__global__ void __launch_bounds__(512, 2)
gemm_qkv(const void* __restrict__ q, const void* __restrict__ wq, u16* __restrict__ Qp,
         const void* __restrict__ k, const void* __restrict__ wk, u16* __restrict__ Kh,
         const void* __restrict__ v, const void* __restrict__ wv, u16* __restrict__ Vt) {
  __shared__ u16 sA[128 * 32];
  __shared__ u16 sB[256 * 32];
  int tileM, tileN;
  tile_remap(tileM, tileN);
  if (blockIdx.z == 0)      gemm_core<IN32, IN32, 0, 0>(sA, sB, q, wq, Qp, tileM, tileN, SCL);
  else if (blockIdx.z == 1) gemm_core<IN32, IN32, 2, 0>(sA, sB, k, wk, Kh, tileM, tileN, 1.f);
  else                      gemm_core<IN32, IN32, 1, 0>(sA, sB, v, wv, Vt, tileM, tileN, 1.f);
}

template <int W32, int O32>
__global__ void __launch_bounds__(512, 2)
gemm_out(const u16* __restrict__ A, const void* __restrict__ W, void* __restrict__ C) {
  __shared__ u16 sA[128 * 32];
  __shared__ u16 sB[256 * 32];
  int tileM, tileN;
  tile_remap(tileM, tileN);
  gemm_core<0, W32, 0, O32>(sA, sB, A, W, C, tileM, tileN, 1.f);
}

// ---------------- Flash attention (unchanged from round 8) ----------------
// 128-thr blocks (2 waves), one 32-row band/block (2048 blocks, heavy-first),
// triple-buffered 32-key tiles, depth-1 prefetch, one barrier/tile.

DEVI void stage_klds(const u16* __restrict__ Kb, const u16* __restrict__ Vb,
                     u16* sKb, u16* sVb, int kt, int w, int lane) {
  const int kr = lane >> 3;
  const int kg = (lane & 7) ^ kr;
  const u16* gk = Kb + (size_t)(kt + w * 16 + kr) * 64 + kg * 8;
  const int vr = lane >> 2;
  const int vg = (lane & 3) ^ ((lane >> 3) & 3);
  const u16* gv = Vb + (size_t)(w * 32 + vr) * 2048 + kt + vg * 8;
  u16* dk = sKb + w * 1024;
  u16* dv = sVb + w * 1024;
  GLDS(gk, dk);
  GLDS(gk + 8 * 64, dk + 512);
  GLDS(gv, dv);
  GLDS(gv + (size_t)16 * 2048, dv + 512);
}

__global__ void __launch_bounds__(128, 3)
attn_kernel(const u16* Qp, const u16* __restrict__ Kh,
            const u16* __restrict__ Vt, u16* AO) {
  __shared__ __align__(16) u16 sK[3][2048];
  __shared__ __align__(16) u16 sV[3][2048];
  const int tid = threadIdx.x;
  const int lane = tid & 63;
  const int w = tid >> 6;
  const int lr = lane & 15;
  const int lg = lane >> 4;

  const int id = blockIdx.x;
  const int xcd = id & 7;
  const int slot = id >> 3;
  const int bh = xcd * 4 + (slot & 3);
  const int band = 63 - (slot >> 2);
  const int b = bh >> 4;
  const int h = bh & 15;
  const int r0 = band * 32;

  const u16* Kb = Kh + (size_t)bh * 2048 * 64;
  const u16* Vb = Vt + (size_t)bh * 64 * 2048;

  const int qrow = r0 + w * 16 + lr;
  const u16* Qw = Qp + ((size_t)(b * 2048 + qrow) << 10) + h * 64;
  const bf16x8 qf0 = *(const bf16x8*)(Qw + lg * 8);
  const bf16x8 qf1 = *(const bf16x8*)(Qw + 32 + lg * 8);

  f32x4 o[4] = {};
  float mr = -INFINITY, ls = 0.f;
  const int nt = band + 1;

  stage_klds(Kb, Vb, sK[0], sV[0], 0, w, lane);

#pragma unroll 1
  for (int t = 0; t < nt; ++t) {
    if (t + 1 < nt) {
      const int bi = (t + 1) % 3;
      stage_klds(Kb, Vb, sK[bi], sV[bi], (t + 1) * 32, w, lane);
      asm volatile("s_waitcnt vmcnt(4)" ::: "memory");
    } else {
      asm volatile("s_waitcnt vmcnt(0)" ::: "memory");
    }
    asm volatile("s_barrier" ::: "memory");
    __builtin_amdgcn_s_setprio(1);

    {
      const int bi = t % 3;
      const u16* sKb = sK[bi];
      const u16* sVb = sV[bi];
      const int sw = lr & 7;
      const bf16x8 kf0 = *(const bf16x8*)(sKb + lr * 64 + ((lg ^ sw) * 8));
      const bf16x8 kf1 = *(const bf16x8*)(sKb + lr * 64 + (((4 + lg) ^ sw) * 8));
      const bf16x8 kf2 = *(const bf16x8*)(sKb + (16 + lr) * 64 + ((lg ^ sw) * 8));
      const bf16x8 kf3 = *(const bf16x8*)(sKb + (16 + lr) * 64 + (((4 + lg) ^ sw) * 8));

      const f32x4 z = {};
      f32x4 s0 = __builtin_amdgcn_mfma_f32_16x16x32_bf16(kf0, qf0, z, 0, 0, 0);
      s0 = __builtin_amdgcn_mfma_f32_16x16x32_bf16(kf1, qf1, s0, 0, 0, 0);
      f32x4 s1 = __builtin_amdgcn_mfma_f32_16x16x32_bf16(kf2, qf0, z, 0, 0, 0);
      s1 = __builtin_amdgcn_mfma_f32_16x16x32_bf16(kf3, qf1, s1, 0, 0, 0);

      float p[8];
#pragma unroll
      for (int j = 0; j < 4; ++j) { p[j] = s0[j]; p[4 + j] = s1[j]; }
      if (t == nt - 1) {
        const int kt0 = t * 32;
#pragma unroll
        for (int j = 0; j < 4; ++j) {
          if (kt0 + lg * 4 + j > qrow)      p[j] = -INFINITY;
          if (kt0 + 16 + lg * 4 + j > qrow) p[4 + j] = -INFINITY;
        }
      }

      const float tm = fmaxf(fmaxf(fmaxf(p[0], p[1]), fmaxf(p[2], p[3])),
                             fmaxf(fmaxf(p[4], p[5]), fmaxf(p[6], p[7])));
      if (!__all(tm <= mr + 11.5f)) {
        float tr_ = fmaxf(tm, __shfl_xor(tm, 16));
        tr_ = fmaxf(tr_, __shfl_xor(tr_, 32));
        const float mn = fmaxf(mr, tr_);
        const float fac = exp2f(mr - mn);
        mr = mn;
        ls *= fac;
#pragma unroll
        for (int j = 0; j < 4; ++j) {
          const float fj = __shfl(fac, lg * 4 + j);
#pragma unroll
          for (int d = 0; d < 4; ++d) o[d][j] *= fj;
        }
      }

#pragma unroll
      for (int i = 0; i < 8; ++i) p[i] = exp2f(p[i] - mr);
      ls += ((p[0] + p[1]) + (p[2] + p[3])) + ((p[4] + p[5]) + (p[6] + p[7]));

      bf16x8 pa;
#pragma unroll
      for (int i = 0; i < 8; ++i) pa[i] = (short)f2bf(p[i]);

      const int s2 = (lr >> 1) & 3;
#pragma unroll
      for (int d = 0; d < 4; ++d) {
        const u16* vrow = sVb + (16 * d + lr) * 32;
        const s16x4 v0 = *(const s16x4*)(vrow + (((lg >> 1) ^ s2) * 8) + (lg & 1) * 4);
        const s16x4 v1 = *(const s16x4*)(vrow + ((((lg >> 1) + 2) ^ s2) * 8) + (lg & 1) * 4);
        bf16x8 vf;
        vf[0] = v0[0]; vf[1] = v0[1]; vf[2] = v0[2]; vf[3] = v0[3];
        vf[4] = v1[0]; vf[5] = v1[1]; vf[6] = v1[2]; vf[7] = v1[3];
        o[d] = __builtin_amdgcn_mfma_f32_16x16x32_bf16(pa, vf, o[d], 0, 0, 0);
      }
    }
    __builtin_amdgcn_s_setprio(0);
  }

  float lt = ls + __shfl_xor(ls, 16);
  lt += __shfl_xor(lt, 32);
  const size_t orow = (size_t)(b * 2048 + r0 + w * 16 + lg * 4);
#pragma unroll
  for (int j = 0; j < 4; ++j) {
    const float inv = 1.0f / __shfl(lt, lg * 4 + j);
#pragma unroll
    for (int d = 0; d < 4; ++d)
      AO[(orow + j) * 1024 + h * 64 + 16 * d + lr] = f2bf(o[d][j] * inv);
  }
}

// Host-side bytes/element detection (capture-safe pure host queries).
static int bytes_per_elem(void* p, long long n, void* pnext) {
  if (pnext) {
    ptrdiff_t d = (char*)pnext - (char*)p;
    if (d == n * 2) return 2;
    if (d == n * 4) return 4;
  }
  size_t sz = 0;
  if (hipMemPtrGetInfo(p, &sz) == hipSuccess && sz >= (size_t)(n * 2)) {
    if (sz < (size_t)(n * 4)) return 2;
    if (sz <= (size_t)(n * 8)) return 4;
  }
  return 4;
}

extern "C" void kernel_launch(void* const* d_in, const int* in_sizes, int n_in,
                              void* d_out, int out_size, void* d_ws, size_t ws_size,
                              hipStream_t stream) {
  void* q  = d_in[0];
  void* k  = d_in[1];
  void* v  = d_in[2];
  // d_in[3] = causal tril mask (int32) -- hardcoded in attn_kernel
  void* wq = d_in[4];
  void* wk = d_in[5];
  void* wv = d_in[6];
  void* wo = d_in[7];

  const int in32 = bytes_per_elem(q, in_sizes[0], k) == 4;
  const int w32  = bytes_per_elem(wq, in_sizes[4], wk) == 4;
  const int o32  = bytes_per_elem(d_out, out_size, nullptr) == 4;

  const size_t SZ = (size_t)4096 * 1024;   // activation elems
  const size_t WZ = (size_t)1024 * 1024;   // weight elems
  u16* Qp = (u16*)d_ws;        // [B,S,D] bf16, pre-scaled by SCL
  u16* Kh = Qp + SZ;           // [B,H,S,DH] bf16
  u16* Vt = (u16*)d_out;       // [B,H,DH,S] bf16 scratch
  u16* AO = Qp;                // attn out aliases Qp

  const size_t need = (5 * SZ + 4 * WZ) * 2;  // 48 MiB
  const bool fast = in32 && w32 && !o32 && ws_size >= need;

  if (fast) {
    u16* Qb  = Kh + SZ;
    u16* Kb  = Qb + SZ;
    u16* Vb  = Kb + SZ;
    u16* Wqb = Vb + SZ;
    u16* Wkb = Wqb + WZ;
    u16* Wvb = Wkb + WZ;
    u16* Wob = Wvb + WZ;
    cvt_all<<<dim3(1024, 7), 256, 0, stream>>>(
        (const float*)q, (const float*)k, (const float*)v, (const float*)wq,
        (const float*)wk, (const float*)wv, (const float*)wo,
        Qb, Kb, Vb, Wqb, Wkb, Wvb, Wob);
    gemm_qkv_bf16<<<dim3(8, 32, 3), 256, 0, stream>>>(Qb, Wqb, Qp, Kb, Wkb, Kh, Vb, Wvb, Vt);
    attn_kernel<<<dim3(2048), 128, 0, stream>>>(Qp, Kh, Vt, AO);
    gemm_out_bf16<<<dim3(8, 32), 256, 0, stream>>>(AO, Wob, (u16*)d_out);
    return;
  }

  // -------- fallback: round-8 path --------
  if (in32)
    gemm_qkv<1><<<dim3(4, 32, 3), 512, 0, stream>>>(q, wq, Qp, k, wk, Kh, v, wv, Vt);
  else
    gemm_qkv<0><<<dim3(4, 32, 3), 512, 0, stream>>>(q, wq, Qp, k, wk, Kh, v, wv, Vt);

  attn_kernel<<<dim3(2048), 128, 0, stream>>>(Qp, Kh, Vt, AO);

  if (w32) {
    if (o32) gemm_out<1, 1><<<dim3(4, 32), 512, 0, stream>>>(AO, wo, d_out);
    else     gemm_out<1, 0><<<dim3(4, 32), 512, 0, stream>>>(AO, wo, d_out);
  } else {
    if (o32) gemm_out<0, 1><<<dim3(4, 32), 512, 0, stream>>>(AO, wo, d_out);
    else     gemm_out<0, 0><<<dim3(4, 32), 512, 0, stream>>>(AO, wo, d_out);
  }
}

// Round 10
// 127.363 us; speedup vs baseline: 1.0759x; 1.0759x over previous
//
#include <hip/hip_runtime.h>
#include <hip/hip_bf16.h>

// B=2, S=2048, D=1024, H=16, DH=64. out = softmax(mask(QK^T/8)) V @ Wo^T, Q=x@Wq^T etc.
// fp32 inputs (detected at launch). Internal: bf16 MFMA, fp32 accum.
// ws (16MB): Qp token-major [B,S,D] (PRE-SCALED 0.125*log2e) + Kh head-major [B,H,S,DH].
// d_out: Vt [B,H,DH,S] scratch, overwritten by final GEMM. AO aliases Qp.
// GEMM: 128x128 tile, 256 thr, reg-staged fp32->bf16, double-buffered LDS,
// ONE barrier/K-step, loads issued before MFMA + cvt/write after (T14 split).

typedef unsigned short u16;
typedef __attribute__((ext_vector_type(8))) short bf16x8;  // 8 bf16 = 4 VGPR
typedef __attribute__((ext_vector_type(4))) float f32x4;   // MFMA C/D frag
typedef __attribute__((ext_vector_type(4))) short s16x4;

#define DEVI static __device__ __forceinline__
#define SCL 0.18033688011112042f  /* 0.125 * log2(e) */
#define GLDS(g, l) __builtin_amdgcn_global_load_lds( \
    (const __attribute__((address_space(1))) unsigned*)(g), \
    (__attribute__((address_space(3))) unsigned*)(l), 16, 0, 0)

DEVI u16 f2bf(float f) {
  __hip_bfloat16 h = __float2bfloat16(f);
  union { __hip_bfloat16 h; u16 u; } c; c.h = h;
  return c.u;
}

DEVI bf16x8 cvt8(f32x4 a, f32x4 b) {
  bf16x8 r;
  r[0] = (short)f2bf(a[0]); r[1] = (short)f2bf(a[1]);
  r[2] = (short)f2bf(a[2]); r[3] = (short)f2bf(a[3]);
  r[4] = (short)f2bf(b[0]); r[5] = (short)f2bf(b[1]);
  r[6] = (short)f2bf(b[2]); r[7] = (short)f2bf(b[3]);
  return r;
}

// Issue the raw loads for one staging pair (2x 8-elem units). No cvt here.
template <int F32>
DEVI void load_pair(f32x4* lo, f32x4* hi, bf16x8* bb, const void* P,
                    size_t o0, size_t o1) {
  if constexpr (F32) {
    const float* p0 = (const float*)P + o0;
    const float* p1 = (const float*)P + o1;
    lo[0] = *(const f32x4*)p0; hi[0] = *(const f32x4*)(p0 + 4);
    lo[1] = *(const f32x4*)p1; hi[1] = *(const f32x4*)(p1 + 4);
  } else {
    bb[0] = *(const bf16x8*)((const u16*)P + o0);
    bb[1] = *(const bf16x8*)((const u16*)P + o1);
  }
}

// Convert (fp32 path) + write to LDS. Called AFTER the MFMA cluster.
template <int F32>
DEVI void finish_pair(f32x4* lo, f32x4* hi, bf16x8* bb, u16* dst, int e0, int e1) {
  if constexpr (F32) { bb[0] = cvt8(lo[0], hi[0]); bb[1] = cvt8(lo[1], hi[1]); }
  *(bf16x8*)(dst + e0) = bb[0];
  *(bf16x8*)(dst + e1) = bb[1];
}

// ---------------- epilogue (C = A @ W^T tile writer) ----------------
// MODE 0: token-major (bf16/f32 per O32), scaled. MODE 1: Vt[((b*16+h)*64+d)*2048+s].
// MODE 2: head-major Kh[((b*16+h)*2048+s)*64+dh].
template <int MODE, int O32>
DEVI void epilogue(f32x4 (&acc)[4][4], void* C, int tileM, int tileN,
                   int wr, int wc, int lr, int lg, float oscale) {
  constexpr int N = 1024;
  if constexpr (MODE == 0) {
#pragma unroll
    for (int m = 0; m < 4; ++m) {
      const int row0 = tileM + wr + m * 16 + lg * 4;
#pragma unroll
      for (int n = 0; n < 4; ++n) {
        const int col = tileN + wc + n * 16 + lr;
#pragma unroll
        for (int j = 0; j < 4; ++j) {
          if constexpr (O32)
            ((float*)C)[(size_t)(row0 + j) * N + col] = acc[m][n][j] * oscale;
          else
            ((u16*)C)[(size_t)(row0 + j) * N + col] = f2bf(acc[m][n][j] * oscale);
        }
      }
    }
  } else if constexpr (MODE == 1) {
    u16* Cv = (u16*)C;
#pragma unroll
    for (int m = 0; m < 4; ++m) {
      const int row0 = tileM + wr + m * 16 + lg * 4;
      const int bb = row0 >> 11, s0 = row0 & 2047;
#pragma unroll
      for (int n = 0; n < 4; ++n) {
        const int col = tileN + wc + n * 16 + lr;
        s16x4 pk;
#pragma unroll
        for (int j = 0; j < 4; ++j) pk[j] = (short)f2bf(acc[m][n][j]);
        *(s16x4*)(Cv + ((size_t)(col + (bb << 10)) << 11) + s0) = pk;
      }
    }
  } else {
    u16* Cv = (u16*)C;
#pragma unroll
    for (int m = 0; m < 4; ++m) {
      const int row0 = tileM + wr + m * 16 + lg * 4;
      const int bb = row0 >> 11, s0 = row0 & 2047;
#pragma unroll
      for (int n = 0; n < 4; ++n) {
        const int col = tileN + wc + n * 16 + lr;
        const size_t base = ((size_t)((bb << 4) + (col >> 6)) * 2048 + s0) * 64 + (col & 63);
#pragma unroll
        for (int j = 0; j < 4; ++j)
          Cv[base + (size_t)j * 64] = f2bf(acc[m][n][j]);
      }
    }
  }
}

// ---------------- pipelined GEMM core: C = A[4096,1024] @ W[1024,1024]^T ----------
template <int A32, int W32, int MODE, int O32>
DEVI void gemm_core(u16* sA0, u16* sA1, u16* sB0, u16* sB1,
                    const void* A, const void* W, void* C,
                    int tileM, int tileN, float oscale) {
  constexpr int K = 1024;
  const int tid = threadIdx.x;       // 0..255
  const int lane = tid & 63;
  const int wave = tid >> 6;         // 0..3
  const int wr = (wave >> 1) * 64;
  const int wc = (wave & 1) * 64;
  const int lr = lane & 15, lg = lane >> 4;

  f32x4 acc[4][4] = {};

  const int e0 = tid * 8;            // A/B tiles 128x32 = 4096 elems, 2 rounds each
  const int e1 = 2048 + tid * 8;
  const int r0 = e0 >> 5, c0 = e0 & 31;
  const int r1 = e1 >> 5, c1 = e1 & 31;
  const size_t oA0 = (size_t)(tileM + r0) * K + c0;
  const size_t oA1 = (size_t)(tileM + r1) * K + c1;
  const size_t oB0 = (size_t)(tileN + r0) * K + c0;
  const size_t oB1 = (size_t)(tileN + r1) * K + c1;

  f32x4 alo[2], ahi[2], blo[2], bhi[2];
  bf16x8 ab[2], bb[2];

  // prologue: stage K-tile 0 into buf0
  load_pair<A32>(alo, ahi, ab, A, oA0, oA1);
  load_pair<W32>(blo, bhi, bb, W, oB0, oB1);
  finish_pair<A32>(alo, ahi, ab, sA0, e0, e1);
  finish_pair<W32>(blo, bhi, bb, sB0, e0, e1);
  __syncthreads();

  for (int k0 = 0; k0 < K; k0 += 32) {
    u16* cA = (k0 & 32) ? sA1 : sA0;
    u16* cB = (k0 & 32) ? sB1 : sB0;
    u16* nA = (k0 & 32) ? sA0 : sA1;
    u16* nB = (k0 & 32) ? sB0 : sB1;

    bf16x8 af[4], bfr[4];
#pragma unroll
    for (int m = 0; m < 4; ++m)
      af[m] = *(const bf16x8*)(cA + (wr + m * 16 + lr) * 32 + lg * 8);
#pragma unroll
    for (int n = 0; n < 4; ++n)
      bfr[n] = *(const bf16x8*)(cB + (wc + n * 16 + lr) * 32 + lg * 8);

    const bool more = (k0 + 32 < K);
    if (more) {  // issue next tile's loads BEFORE the MFMA cluster
      load_pair<A32>(alo, ahi, ab, A, oA0 + k0 + 32, oA1 + k0 + 32);
      load_pair<W32>(blo, bhi, bb, W, oB0 + k0 + 32, oB1 + k0 + 32);
    }

#pragma unroll
    for (int m = 0; m < 4; ++m)
#pragma unroll
      for (int n = 0; n < 4; ++n)
        acc[m][n] = __builtin_amdgcn_mfma_f32_16x16x32_bf16(af[m], bfr[n], acc[m][n], 0, 0, 0);

    if (more) {  // cvt + write to the OTHER buffer (no conflict with readers)
      finish_pair<A32>(alo, ahi, ab, nA, e0, e1);
      finish_pair<W32>(blo, bhi, bb, nB, e0, e1);
    }
    __syncthreads();  // one barrier per K-step
  }
  epilogue<MODE, O32>(acc, C, tileM, tileN, wr, wc, lr, lg, oscale);
}

// XCD-local remap (id%8 = XCD round-robin): XCD c owns M-panels 4c..4c+3, all 8 N.
DEVI void tile_remap(int& tileM, int& tileN) {
  const int i = blockIdx.x + 8 * blockIdx.y;  // 0..255; XCD = i & 7
  const int c = i & 7, s = i >> 3;            // s: 0..31
  tileM = (c * 4 + (s & 3)) * 128;
  tileN = (s >> 2) * 128;
}

template <int IN32>
__global__ void __launch_bounds__(256, 3)
gemm_qkv(const void* __restrict__ q, const void* __restrict__ wq, u16* __restrict__ Qp,
         const void* __restrict__ k, const void* __restrict__ wk, u16* __restrict__ Kh,
         const void* __restrict__ v, const void* __restrict__ wv, u16* __restrict__ Vt) {
  __shared__ __align__(16) u16 sA[2][128 * 32];
  __shared__ __align__(16) u16 sB[2][128 * 32];
  int tileM, tileN;
  tile_remap(tileM, tileN);
  if (blockIdx.z == 0)
    gemm_core<IN32, IN32, 0, 0>(sA[0], sA[1], sB[0], sB[1], q, wq, Qp, tileM, tileN, SCL);
  else if (blockIdx.z == 1)
    gemm_core<IN32, IN32, 2, 0>(sA[0], sA[1], sB[0], sB[1], k, wk, Kh, tileM, tileN, 1.f);
  else
    gemm_core<IN32, IN32, 1, 0>(sA[0], sA[1], sB[0], sB[1], v, wv, Vt, tileM, tileN, 1.f);
}

template <int W32, int O32>
__global__ void __launch_bounds__(256, 3)
gemm_out(const u16* __restrict__ A, const void* __restrict__ W, void* __restrict__ C) {
  __shared__ __align__(16) u16 sA[2][128 * 32];
  __shared__ __align__(16) u16 sB[2][128 * 32];
  int tileM, tileN;
  tile_remap(tileM, tileN);
  gemm_core<0, W32, 0, O32>(sA[0], sA[1], sB[0], sB[1], A, W, C, tileM, tileN, 1.f);
}

// ---------------- Flash attention (unchanged from round 8) ----------------
// 128-thr blocks (2 waves), one 32-row band/block (2048 blocks, heavy-first),
// triple-buffered 32-key tiles, depth-1 prefetch, one barrier/tile.

DEVI void stage_klds(const u16* __restrict__ Kb, const u16* __restrict__ Vb,
                     u16* sKb, u16* sVb, int kt, int w, int lane) {
  const int kr = lane >> 3;
  const int kg = (lane & 7) ^ kr;
  const u16* gk = Kb + (size_t)(kt + w * 16 + kr) * 64 + kg * 8;
  const int vr = lane >> 2;
  const int vg = (lane & 3) ^ ((lane >> 3) & 3);
  const u16* gv = Vb + (size_t)(w * 32 + vr) * 2048 + kt + vg * 8;
  u16* dk = sKb + w * 1024;
  u16* dv = sVb + w * 1024;
  GLDS(gk, dk);
  GLDS(gk + 8 * 64, dk + 512);
  GLDS(gv, dv);
  GLDS(gv + (size_t)16 * 2048, dv + 512);
}

__global__ void __launch_bounds__(128, 3)
attn_kernel(const u16* Qp, const u16* __restrict__ Kh,
            const u16* __restrict__ Vt, u16* AO) {
  __shared__ __align__(16) u16 sK[3][2048];
  __shared__ __align__(16) u16 sV[3][2048];
  const int tid = threadIdx.x;
  const int lane = tid & 63;
  const int w = tid >> 6;
  const int lr = lane & 15;
  const int lg = lane >> 4;

  const int id = blockIdx.x;
  const int xcd = id & 7;
  const int slot = id >> 3;
  const int bh = xcd * 4 + (slot & 3);
  const int band = 63 - (slot >> 2);
  const int b = bh >> 4;
  const int h = bh & 15;
  const int r0 = band * 32;

  const u16* Kb = Kh + (size_t)bh * 2048 * 64;
  const u16* Vb = Vt + (size_t)bh * 64 * 2048;

  const int qrow = r0 + w * 16 + lr;
  const u16* Qw = Qp + ((size_t)(b * 2048 + qrow) << 10) + h * 64;
  const bf16x8 qf0 = *(const bf16x8*)(Qw + lg * 8);
  const bf16x8 qf1 = *(const bf16x8*)(Qw + 32 + lg * 8);

  f32x4 o[4] = {};
  float mr = -INFINITY, ls = 0.f;
  const int nt = band + 1;

  stage_klds(Kb, Vb, sK[0], sV[0], 0, w, lane);

#pragma unroll 1
  for (int t = 0; t < nt; ++t) {
    if (t + 1 < nt) {
      const int bi = (t + 1) % 3;
      stage_klds(Kb, Vb, sK[bi], sV[bi], (t + 1) * 32, w, lane);
      asm volatile("s_waitcnt vmcnt(4)" ::: "memory");
    } else {
      asm volatile("s_waitcnt vmcnt(0)" ::: "memory");
    }
    asm volatile("s_barrier" ::: "memory");
    __builtin_amdgcn_s_setprio(1);

    {
      const int bi = t % 3;
      const u16* sKb = sK[bi];
      const u16* sVb = sV[bi];
      const int sw = lr & 7;
      const bf16x8 kf0 = *(const bf16x8*)(sKb + lr * 64 + ((lg ^ sw) * 8));
      const bf16x8 kf1 = *(const bf16x8*)(sKb + lr * 64 + (((4 + lg) ^ sw) * 8));
      const bf16x8 kf2 = *(const bf16x8*)(sKb + (16 + lr) * 64 + ((lg ^ sw) * 8));
      const bf16x8 kf3 = *(const bf16x8*)(sKb + (16 + lr) * 64 + (((4 + lg) ^ sw) * 8));

      const f32x4 z = {};
      f32x4 s0 = __builtin_amdgcn_mfma_f32_16x16x32_bf16(kf0, qf0, z, 0, 0, 0);
      s0 = __builtin_amdgcn_mfma_f32_16x16x32_bf16(kf1, qf1, s0, 0, 0, 0);
      f32x4 s1 = __builtin_amdgcn_mfma_f32_16x16x32_bf16(kf2, qf0, z, 0, 0, 0);
      s1 = __builtin_amdgcn_mfma_f32_16x16x32_bf16(kf3, qf1, s1, 0, 0, 0);

      float p[8];
#pragma unroll
      for (int j = 0; j < 4; ++j) { p[j] = s0[j]; p[4 + j] = s1[j]; }
      if (t == nt - 1) {
        const int kt0 = t * 32;
#pragma unroll
        for (int j = 0; j < 4; ++j) {
          if (kt0 + lg * 4 + j > qrow)      p[j] = -INFINITY;
          if (kt0 + 16 + lg * 4 + j > qrow) p[4 + j] = -INFINITY;
        }
      }

      const float tm = fmaxf(fmaxf(fmaxf(p[0], p[1]), fmaxf(p[2], p[3])),
                             fmaxf(fmaxf(p[4], p[5]), fmaxf(p[6], p[7])));
      if (!__all(tm <= mr + 11.5f)) {
        float tr_ = fmaxf(tm, __shfl_xor(tm, 16));
        tr_ = fmaxf(tr_, __shfl_xor(tr_, 32));
        const float mn = fmaxf(mr, tr_);
        const float fac = exp2f(mr - mn);
        mr = mn;
        ls *= fac;
#pragma unroll
        for (int j = 0; j < 4; ++j) {
          const float fj = __shfl(fac, lg * 4 + j);
#pragma unroll
          for (int d = 0; d < 4; ++d) o[d][j] *= fj;
        }
      }

#pragma unroll
      for (int i = 0; i < 8; ++i) p[i] = exp2f(p[i] - mr);
      ls += ((p[0] + p[1]) + (p[2] + p[3])) + ((p[4] + p[5]) + (p[6] + p[7]));

      bf16x8 pa;
#pragma unroll
      for (int i = 0; i < 8; ++i) pa[i] = (short)f2bf(p[i]);

      const int s2 = (lr >> 1) & 3;
#pragma unroll
      for (int d = 0; d < 4; ++d) {
        const u16* vrow = sVb + (16 * d + lr) * 32;
        const s16x4 v0 = *(const s16x4*)(vrow + (((lg >> 1) ^ s2) * 8) + (lg & 1) * 4);
        const s16x4 v1 = *(const s16x4*)(vrow + ((((lg >> 1) + 2) ^ s2) * 8) + (lg & 1) * 4);
        bf16x8 vf;
        vf[0] = v0[0]; vf[1] = v0[1]; vf[2] = v0[2]; vf[3] = v0[3];
        vf[4] = v1[0]; vf[5] = v1[1]; vf[6] = v1[2]; vf[7] = v1[3];
        o[d] = __builtin_amdgcn_mfma_f32_16x16x32_bf16(pa, vf, o[d], 0, 0, 0);
      }
    }
    __builtin_amdgcn_s_setprio(0);
  }

  float lt = ls + __shfl_xor(ls, 16);
  lt += __shfl_xor(lt, 32);
  const size_t orow = (size_t)(b * 2048 + r0 + w * 16 + lg * 4);
#pragma unroll
  for (int j = 0; j < 4; ++j) {
    const float inv = 1.0f / __shfl(lt, lg * 4 + j);
#pragma unroll
    for (int d = 0; d < 4; ++d)
      AO[(orow + j) * 1024 + h * 64 + 16 * d + lr] = f2bf(o[d][j] * inv);
  }
}

// Host-side bytes/element detection (capture-safe pure host queries).
static int bytes_per_elem(void* p, long long n, void* pnext) {
  if (pnext) {
    ptrdiff_t d = (char*)pnext - (char*)p;
    if (d == n * 2) return 2;
    if (d == n * 4) return 4;
  }
  size_t sz = 0;
  if (hipMemPtrGetInfo(p, &sz) == hipSuccess && sz >= (size_t)(n * 2)) {
    if (sz < (size_t)(n * 4)) return 2;
    if (sz <= (size_t)(n * 8)) return 4;
  }
  return 4;
}

extern "C" void kernel_launch(void* const* d_in, const int* in_sizes, int n_in,
                              void* d_out, int out_size, void* d_ws, size_t ws_size,
                              hipStream_t stream) {
  void* q  = d_in[0];
  void* k  = d_in[1];
  void* v  = d_in[2];
  // d_in[3] = causal tril mask (int32) -- hardcoded in attn_kernel
  void* wq = d_in[4];
  void* wk = d_in[5];
  void* wv = d_in[6];
  void* wo = d_in[7];

  const int in32 = bytes_per_elem(q, in_sizes[0], k) == 4;
  const int w32  = bytes_per_elem(wq, in_sizes[4], wk) == 4;
  const int o32  = bytes_per_elem(d_out, out_size, nullptr) == 4;

  const size_t SZ = (size_t)4096 * 1024;
  u16* Qp = (u16*)d_ws;        // [B,S,D] bf16, pre-scaled by SCL
  u16* Kh = Qp + SZ;           // [B,H,S,DH] bf16
  u16* Vt = (u16*)d_out;       // [B,H,DH,S] bf16 scratch
  u16* AO = Qp;                // attn out aliases Qp

  if (in32)
    gemm_qkv<1><<<dim3(8, 32, 3), 256, 0, stream>>>(q, wq, Qp, k, wk, Kh, v, wv, Vt);
  else
    gemm_qkv<0><<<dim3(8, 32, 3), 256, 0, stream>>>(q, wq, Qp, k, wk, Kh, v, wv, Vt);

  attn_kernel<<<dim3(2048), 128, 0, stream>>>(Qp, Kh, Vt, AO);

  if (w32) {
    if (o32) gemm_out<1, 1><<<dim3(8, 32), 256, 0, stream>>>(AO, wo, d_out);
    else     gemm_out<1, 0><<<dim3(8, 32), 256, 0, stream>>>(AO, wo, d_out);
  } else {
    if (o32) gemm_out<0, 1><<<dim3(8, 32), 256, 0, stream>>>(AO, wo, d_out);
    else     gemm_out<0, 0><<<dim3(8, 32), 256, 0, stream>>>(AO, wo, d_out);
  }
}